// Round 11
// baseline (326.084 us; speedup 1.0000x reference)
//
#include <hip/hip_runtime.h>
#include <math.h>

// Problem constants (reference: B,H,Q_TOK,D = 8,12,577,64)
constexpr int BB = 8, HH = 12, QT = 577, DD = 64;
constexpr int NTOK = BB * HH * QT;                        // 55392 tokens
constexpr long long MASK_ELEMS = (long long)NTOK * QT;    // 31,961,184
constexpr int NBH = BB * HH;                              // 96 bh-rows per q
constexpr int ROWS_PER_BLOCK = 16;                        // 8 waves x 2 rows
constexpr int CHUNKS = NBH / ROWS_PER_BLOCK;              // 6

using f4 = __attribute__((ext_vector_type(4))) float;
using f2 = __attribute__((ext_vector_type(2))) float;

// Verified mask math (R2-R10, minimal lowering): j's prescaled by log2e;
// E = 2^(j0*g0+j1*g1+j2*g2) = 1/p; mask = u/(u+(E-1)*(1-u)) [T==1] via rcp.
// Edges exact: hq2==0 -> E=1 -> m~=1 (ref 1.0); E=inf -> m=0 (ref 0).
template<bool T1>
__device__ __forceinline__ float mask_elem(float g0, float g1, float g2,
                                           float j0, float j1, float j2,
                                           float uv, float invT)
{
    const float hq2 = fmaxf(fmaf(j2, g2, fmaf(j1, g1, j0 * g0)), 0.0f);
    const float E   = __builtin_amdgcn_exp2f(hq2);   // 2^hq2, exact 1 at 0
    const float a   = E - 1.0f;
    if (T1) {
        const float den = fmaf(a, 1.0f - uv, uv);
        return uv * __builtin_amdgcn_rcpf(den);      // v_rcp + v_mul
    }
    const float rr = a * (1.0f - uv) * __builtin_amdgcn_rcpf(uv);
    const float pw = __builtin_amdgcn_exp2f(__builtin_amdgcn_logf(rr) * invT);
    return __builtin_amdgcn_rcpf(1.0f + pw);
}

// TWO rows (same q, bh and bh+8 -> identical alignment phase h since
// 577 = 1 mod 4 and 8 = 0 mod 4) share each dists load and its g0/g1/g2.
template<bool T1>
__device__ __forceinline__ void mask_pair(int NV, int lane, int idx2,
                                          const f4* uuA, const f4* uuB,
                                          int scnt, int ks, float usA, float usB,
                                          const float* __restrict__ dq, int h,
                                          float jA0, float jA1, float jA2,
                                          float jB0, float jB1, float jB2,
                                          float invT,
                                          float* __restrict__ mpA,
                                          float* __restrict__ mpB,
                                          float* __restrict__ out,
                                          unsigned baseA, unsigned baseB)
{
    // element k = h + 256*p + 4*lane + c -> float off 2h + 512p + 8*lane + 2c
    const float* __restrict__ dp0 = dq + 2 * h + 8 * lane;
#pragma unroll
    for (int p = 0; p < 2; ++p) {
        const float* __restrict__ dp = dp0 + 512 * p;
        f4 mA, mB;
#pragma unroll
        for (int c = 0; c < 4; ++c) {
            const f2 d = *(const f2*)(dp + 2 * c);           // 8B-aligned
            const float g0 = d.x * d.x, g1 = d.x * d.y, g2 = d.y * d.y;
            mA[c] = mask_elem<T1>(g0, g1, g2, jA0, jA1, jA2, uuA[p][c], invT);
            mB[c] = mask_elem<T1>(g0, g1, g2, jB0, jB1, jB2, uuB[p][c], invT);
        }
        __builtin_nontemporal_store(mA, (f4*)(mpA + 4 * (64 * p + lane)));
        __builtin_nontemporal_store(mB, (f4*)(mpB + 4 * (64 * p + lane)));
    }
    if (idx2 < NV) {                             // pass 2: lanes 0..14/15
        const float* __restrict__ dp = dp0 + 1024;
        f4 mA, mB;
#pragma unroll
        for (int c = 0; c < 4; ++c) {
            const f2 d = *(const f2*)(dp + 2 * c);
            const float g0 = d.x * d.x, g1 = d.x * d.y, g2 = d.y * d.y;
            mA[c] = mask_elem<T1>(g0, g1, g2, jA0, jA1, jA2, uuA[2][c], invT);
            mB[c] = mask_elem<T1>(g0, g1, g2, jB0, jB1, jB2, uuB[2][c], invT);
        }
        __builtin_nontemporal_store(mA, (f4*)(mpA + 4 * idx2));
        __builtin_nontemporal_store(mB, (f4*)(mpB + 4 * idx2));
    }
    if (lane < scnt) {                           // head/tail leftovers (1 or 5)
        const f2 d = *(const f2*)(dq + 2 * ks);
        const float g0 = d.x * d.x, g1 = d.x * d.y, g2 = d.y * d.y;
        __builtin_nontemporal_store(
            mask_elem<T1>(g0, g1, g2, jA0, jA1, jA2, usA, invT), out + baseA + ks);
        __builtin_nontemporal_store(
            mask_elem<T1>(g0, g1, g2, jB0, jB1, jB2, usB, invT), out + baseB + ks);
    }
}

// ---------------------------------------------------------------------------
// FUSED v5 = verified R10 math + TWO ROWS PER WAVE:
//  - one W1 ds_read feeds BOTH MLP fma chains (2x ILP on the serial chain),
//  - one dists load + one (g0,g1,g2) feeds BOTH rows' mask elements,
//  - 6 u-row dwordx4 in flight per wave (2x Little's-law depth),
//  - W1 stage + barrier amortized over 16 rows/block instead of 8.
// u loads are PLAIN again (R9's nontemporal bypassed the L3, +16 MB HBM).
// ---------------------------------------------------------------------------
__global__ __launch_bounds__(512, 6)
void fused_v5(const float* __restrict__ query,  // (NTOK, 64)
              const float* __restrict__ W1,     // (64, 64)
              const float* __restrict__ b1,     // (64)
              const float* __restrict__ W2,     // (64, 3)
              const float* __restrict__ b2,     // (3)
              const float* __restrict__ dists,  // (577, 577, 2) zero-padded CLS
              const float* __restrict__ u,      // (NTOK*577) flat
              const float* __restrict__ temp,   // (1)
              float* __restrict__ out)          // mask then Sigma
{
    __shared__ float W1s[DD * DD];               // 16 KB

    f4* __restrict__ SigOut = (f4*)(out + MASK_ELEMS);
    const int q     = blockIdx.x;                // 0..576
    const int chunk = blockIdx.y;                // 0..5
    const int tid   = threadIdx.x;
    const int wave  = tid >> 6, lane = tid & 63;

    const int r0 = chunk * ROWS_PER_BLOCK + wave;       // bh row A
    const int r1 = r0 + 8;                               // bh row B (same h)
    const int tokenA = r0 * QT + q, tokenB = r1 * QT + q;
    const unsigned baseA = (unsigned)tokenA * (unsigned)QT;
    const unsigned baseB = (unsigned)tokenB * (unsigned)QT;  // = baseA + 2663432
    const int h  = (int)((0u - baseA) & 3u);     // same for both rows
    const int NV = (QT - h) >> 2;                // 143 or 144 vec4s
    const float* __restrict__ upA = u   + baseA + h;
    const float* __restrict__ upB = u   + baseB + h;
    float*       __restrict__ mpA = out + baseA + h;
    float*       __restrict__ mpB = out + baseB + h;
    const float* __restrict__ dq  = dists + (unsigned)q * 1154u;

    // ---- phase 0: stage W1 -> LDS; load both query elements ----
    ((f4*)W1s)[tid]       = ((const f4*)W1)[tid];
    ((f4*)W1s)[tid + 512] = ((const f4*)W1)[tid + 512];
    const float qvA  = query[(size_t)tokenA * DD + lane];
    const float qvB  = query[(size_t)tokenB * DD + lane];
    const float tval = temp[0];
    __syncthreads();                             // drains only the small stage

    // ---- phase 2a: issue all 6 u-row vec4 loads (plain: L3 absorbs) ----
    f4 uuA[3], uuB[3];
    uuA[0] = *(const f4*)(upA + 4 * lane);
    uuB[0] = *(const f4*)(upB + 4 * lane);
    uuA[1] = *(const f4*)(upA + 4 * (64 + lane));
    uuB[1] = *(const f4*)(upB + 4 * (64 + lane));
    const int idx2 = 128 + lane;
    uuA[2] = {}; uuB[2] = {};
    if (idx2 < NV) {
        uuA[2] = *(const f4*)(upA + 4 * idx2);
        uuB[2] = *(const f4*)(upB + 4 * idx2);
    }
    const int scnt = QT - 4 * NV;                // 1 or 5 leftovers
    int ks = 0; float usA = 0.0f, usB = 0.0f;
    if (lane < scnt) {
        ks  = (lane < h) ? lane : (h + 4 * NV + (lane - h));
        usA = u[baseA + ks];
        usB = u[baseB + ks];
    }

    // ---- phase 2b: dual MLP; one ds_read feeds both fma chains ----
    float acc0 = b1[lane], acc1 = acc0;
#pragma unroll
    for (int i = 0; i < DD; ++i) {
        const float w  = W1s[i * DD + lane];     // shared ds_read_b32
        const float x0 = __int_as_float(
            __builtin_amdgcn_readlane(__float_as_int(qvA), i));
        const float x1 = __int_as_float(
            __builtin_amdgcn_readlane(__float_as_int(qvB), i));
        acc0 = fmaf(x0, w, acc0);
        acc1 = fmaf(x1, w, acc1);
    }
    const float hg0 = 0.5f * acc0 * (1.0f + erff(acc0 * 0.7071067811865476f));
    const float hg1 = 0.5f * acc1 * (1.0f + erff(acc1 * 0.7071067811865476f));

    const float w20 = W2[lane * 3 + 0], w21 = W2[lane * 3 + 1],
                w22 = W2[lane * 3 + 2];
    float pA0 = hg0 * w20, pA1 = hg0 * w21, pA2 = hg0 * w22;
    float pB0 = hg1 * w20, pB1 = hg1 * w21, pB2 = hg1 * w22;
#pragma unroll
    for (int off = 32; off > 0; off >>= 1) {     // butterflies: all lanes get sums
        pA0 += __shfl_xor(pA0, off);
        pA1 += __shfl_xor(pA1, off);
        pA2 += __shfl_xor(pA2, off);
        pB0 += __shfl_xor(pB0, off);
        pB1 += __shfl_xor(pB1, off);
        pB2 += __shfl_xor(pB2, off);
    }
    const float b20 = b2[0], b21 = b2[1], b22 = b2[2];

    const float syA  = expf(pA0 + b20) + 1.0f;   // precise ocml for Sigma
    const float sxA  = expf(pA1 + b21) + 1.0f;
    const float rhoA = tanhf(pA2 + b22) * 0.99f;
    const float covA = syA * sxA * rhoA;
    const float SxA = syA * syA, SwA = sxA * sxA, SyA = covA;
    const float syB  = expf(pB0 + b20) + 1.0f;
    const float sxB  = expf(pB1 + b21) + 1.0f;
    const float rhoB = tanhf(pB2 + b22) * 0.99f;
    const float covB = syB * sxB * rhoB;
    const float SxB = syB * syB, SwB = sxB * sxB, SyB = covB;
    if (lane == 0) {
        f4 sA; sA.x = SxA; sA.y = SyA; sA.z = SyA; sA.w = SwA;
        f4 sB; sB.x = SxB; sB.y = SyB; sB.z = SyB; sB.w = SwB;
        SigOut[tokenA] = sA;
        SigOut[tokenB] = sB;
    }

    constexpr float L2E = 1.4426950408889634f;   // log2(e), folded into j's
    const float rdA = __fdividef(1.0f, fmaf(SxA, SwA, -SyA * SyA));
    const float jA0 =  0.5f * SwA * rdA * L2E;
    const float jA1 = -SyA * rdA * L2E;
    const float jA2 =  0.5f * SxA * rdA * L2E;
    const float rdB = __fdividef(1.0f, fmaf(SxB, SwB, -SyB * SyB));
    const float jB0 =  0.5f * SwB * rdB * L2E;
    const float jB1 = -SyB * rdB * L2E;
    const float jB2 =  0.5f * SxB * rdB * L2E;

    // scalar-uniform temperature branch: hot path has NO predicated cold ops
    const float invT = __int_as_float(__builtin_amdgcn_readfirstlane(
                           __float_as_int(__fdividef(1.0f, tval))));
    if (invT == 1.0f)
        mask_pair<true >(NV, lane, idx2, uuA, uuB, scnt, ks, usA, usB, dq, h,
                         jA0, jA1, jA2, jB0, jB1, jB2, invT,
                         mpA, mpB, out, baseA, baseB);
    else
        mask_pair<false>(NV, lane, idx2, uuA, uuB, scnt, ks, usA, usB, dq, h,
                         jA0, jA1, jA2, jB0, jB1, jB2, invT,
                         mpA, mpB, out, baseA, baseB);
}

extern "C" void kernel_launch(void* const* d_in, const int* in_sizes, int n_in,
                              void* d_out, int out_size, void* d_ws, size_t ws_size,
                              hipStream_t stream) {
    const float* query = (const float*)d_in[0];
    const float* W1    = (const float*)d_in[1];
    const float* b1    = (const float*)d_in[2];
    const float* W2    = (const float*)d_in[3];
    const float* b2    = (const float*)d_in[4];
    const float* dists = (const float*)d_in[5];
    const float* u     = (const float*)d_in[6];
    const float* temp  = (const float*)d_in[7];
    float* out = (float*)d_out;

    fused_v5<<<dim3(QT, CHUNKS), dim3(512), 0, stream>>>(
        query, W1, b1, W2, b2, dists, u, temp, out);
}